// Round 4
// baseline (601.823 us; speedup 1.0000x reference)
//
#include <hip/hip_runtime.h>
#include <stdint.h>

typedef __bf16 bf16;
typedef __bf16 bf16x8 __attribute__((ext_vector_type(8)));
typedef float f32x4 __attribute__((ext_vector_type(4)));

__device__ __forceinline__ float bfbits2f(uint32_t lo16) {
    uint32_t b = lo16 << 16;
    float f;
    __builtin_memcpy(&f, &b, 4);
    return f;
}

__device__ __forceinline__ uint32_t pack2bf(float a, float b) {
    uint32_t lo = __builtin_bit_cast(unsigned short, (bf16)a);
    uint32_t hi = __builtin_bit_cast(unsigned short, (bf16)b);
    return lo | (hi << 16);
}

// ---- prep: W1T[h][f]=W1[f][h];  WcatT2[o][r*128+c]=weight[r][c][o], WcatT2[o][R*128+c]=root[c][o]
__global__ void k_prep(const float* __restrict__ W1, const float* __restrict__ weight,
                       const float* __restrict__ root, bf16* __restrict__ W1T,
                       bf16* __restrict__ WcatT2, int R, int ldt) {
    int total = 16384 * (R + 2);
    for (int i = blockIdx.x * blockDim.x + threadIdx.x; i < total; i += gridDim.x * blockDim.x) {
        if (i < 16384) {
            int f = i >> 7, h = i & 127;
            W1T[h * 128 + f] = (bf16)W1[f * 128 + h];
        } else {
            int j = i - 16384;
            int r = j >> 14, rem = j & 16383, c = rem >> 7, o = rem & 127;
            float v = (r < R) ? weight[(size_t)(r * 128 + c) * 128 + o] : root[c * 128 + o];
            WcatT2[(size_t)o * ldt + r * 128 + c] = (bf16)v;
        }
    }
}

// q[i] = sum_j W2[i][j]*Wo[j];  qc[128] = b2.Wo + bo
__global__ void k_qprep(const float* __restrict__ W2, const float* __restrict__ b2,
                        const float* __restrict__ Wo, const float* __restrict__ bo,
                        float* __restrict__ qc) {
    int i = threadIdx.x;
    float s = 0.f;
    for (int j = 0; j < 128; j++) s += W2[i * 128 + j] * Wo[j];
    qc[i] = s;
    if (i == 0) {
        float c = bo[0];
        for (int j = 0; j < 128; j++) c += b2[j] * Wo[j];
        qc[128] = c;
    }
}

// ---- CSR build over segments seg = r*N + dst (relation-major; within a
// relation edges are grouped by ascending dst -> contiguous per node range) ----
__global__ void k_hist(const int* __restrict__ dst, const int* __restrict__ etype,
                       int* __restrict__ cnt, int E, int N) {
    for (int e = blockIdx.x * blockDim.x + threadIdx.x; e < E; e += gridDim.x * blockDim.x)
        atomicAdd(&cnt[etype[e] * N + dst[e]], 1);
}

__global__ __launch_bounds__(256) void k_scan_blk(const int* __restrict__ cnt, int* __restrict__ bsum, int M) {
    int i = blockIdx.x * 256 + threadIdx.x;
    int v = (i < M) ? cnt[i] : 0;
#pragma unroll
    for (int d = 1; d < 64; d <<= 1) v += __shfl_xor(v, d);
    __shared__ int ws[4];
    if ((threadIdx.x & 63) == 0) ws[threadIdx.x >> 6] = v;
    __syncthreads();
    if (threadIdx.x == 0) bsum[blockIdx.x] = ws[0] + ws[1] + ws[2] + ws[3];
}

// looped single-block exclusive scan over nb block sums
__global__ __launch_bounds__(256) void k_scan_top(int* __restrict__ bsum, int nb) {
    __shared__ int s[256];
    __shared__ int carry;
    int t = threadIdx.x;
    if (t == 0) carry = 0;
    __syncthreads();
    for (int base = 0; base < nb; base += 256) {
        int i = base + t;
        int v = (i < nb) ? bsum[i] : 0;
        s[t] = v;
        __syncthreads();
#pragma unroll
        for (int d = 1; d < 256; d <<= 1) {
            int u = (t >= d) ? s[t - d] : 0;
            __syncthreads();
            s[t] += u;
            __syncthreads();
        }
        int excl = carry + s[t] - v;
        int tot = s[255];
        __syncthreads();
        if (i < nb) bsum[i] = excl;
        if (t == 0) carry += tot;
        __syncthreads();
    }
}

__global__ __launch_bounds__(256) void k_scan_apply(const int* __restrict__ cnt, const int* __restrict__ bsum,
                                                    int* __restrict__ row_off, int* __restrict__ cursor, int M) {
    int b = blockIdx.x, t = threadIdx.x;
    int i = b * 256 + t;
    int v = (i < M) ? cnt[i] : 0;
    int lane = t & 63, wid = t >> 6;
    int incl = v;
#pragma unroll
    for (int d = 1; d < 64; d <<= 1) {
        int u = __shfl_up(incl, d);
        if (lane >= d) incl += u;
    }
    __shared__ int ws[4];
    if (lane == 63) ws[wid] = incl;
    __syncthreads();
    int woff = 0;
    for (int wj = 0; wj < 4; wj++)
        if (wj < wid) woff += ws[wj];
    int excl = bsum[b] + woff + incl - v;
    if (i < M) {
        row_off[i] = excl;
        cursor[i] = excl;
        if (i == M - 1) row_off[M] = excl + v;
    }
}

// XCD-partitioned CSR fill. payload = (dst<<16)|src (requires N <= 65536).
__global__ void k_fill(const int* __restrict__ src, const int* __restrict__ dst,
                       const int* __restrict__ etype, int* __restrict__ cursor,
                       int* __restrict__ csr, int E, int N, int pbase) {
    int p = blockIdx.x & 7;
    int bg = blockIdx.x >> 3;
    int nchunk = gridDim.x >> 3;
    int chunk = (E + nchunk - 1) / nchunk;
    int beg = bg * chunk, end = min(beg + chunk, E);
    int lo = p * pbase, hi = lo + pbase;
    for (int e = beg + (int)threadIdx.x; e < end; e += blockDim.x) {
        int d = dst[e];
        int seg = etype[e] * N + d;
        if (seg >= lo && seg < hi) {
            int pos = atomicAdd(&cursor[seg], 1);
            csr[pos] = (int)(((uint32_t)d << 16) | (uint32_t)src[e]);
        }
    }
}

// ---- GEMM (layer 0): C[M x 128] = A_f32[M x 128] * B[128 x 128] (+bias), bf16 out
__global__ __launch_bounds__(256) void k_gemm0(const float* __restrict__ A, const bf16* __restrict__ BT,
                                               const float* __restrict__ bias, bf16* __restrict__ C, int M) {
    __shared__ bf16 sA[128 * 128];
    __shared__ bf16 sB[128 * 128];
    int tid = threadIdx.x;
    int m0 = blockIdx.x * 128;
#pragma unroll
    for (int i = 0; i < 8; i++) {
        int chunk = i * 256 + tid;
        int row = chunk >> 4, c16 = chunk & 15;
        int sw = ((c16 ^ (row & 7)) << 3);
        int gr = m0 + row;
        int4 va = {0, 0, 0, 0};
        if (gr < M) {
            const float* ap = A + (size_t)gr * 128 + (c16 << 3);
            float4 f0 = *reinterpret_cast<const float4*>(ap);
            float4 f1 = *reinterpret_cast<const float4*>(ap + 4);
            bf16 tmp[8] = {(bf16)f0.x, (bf16)f0.y, (bf16)f0.z, (bf16)f0.w,
                           (bf16)f1.x, (bf16)f1.y, (bf16)f1.z, (bf16)f1.w};
            __builtin_memcpy(&va, tmp, 16);
        }
        *reinterpret_cast<int4*>(&sA[row * 128 + sw]) = va;
        int4 vb = *reinterpret_cast<const int4*>(&BT[(size_t)row * 128 + (c16 << 3)]);
        *reinterpret_cast<int4*>(&sB[row * 128 + sw]) = vb;
    }
    __syncthreads();

    int lane = tid & 63, w = tid >> 6;
    int wm = (w >> 1) * 64, wn = (w & 1) * 64;
    int lr = lane & 15, lk = lane >> 4;
    f32x4 zero = {0.f, 0.f, 0.f, 0.f};
    f32x4 acc[4][4];
#pragma unroll
    for (int mi = 0; mi < 4; mi++)
#pragma unroll
        for (int ni = 0; ni < 4; ni++) acc[mi][ni] = zero;

#pragma unroll
    for (int kk = 0; kk < 4; kk++) {
        int c = (kk << 2) + lk;
        bf16x8 af[4], bfr[4];
#pragma unroll
        for (int mi = 0; mi < 4; mi++) {
            int r = wm + mi * 16 + lr;
            af[mi] = *reinterpret_cast<const bf16x8*>(&sA[r * 128 + ((c ^ (r & 7)) << 3)]);
        }
#pragma unroll
        for (int ni = 0; ni < 4; ni++) {
            int r = wn + ni * 16 + lr;
            bfr[ni] = *reinterpret_cast<const bf16x8*>(&sB[r * 128 + ((c ^ (r & 7)) << 3)]);
        }
#pragma unroll
        for (int mi = 0; mi < 4; mi++)
#pragma unroll
            for (int ni = 0; ni < 4; ni++)
                acc[mi][ni] = __builtin_amdgcn_mfma_f32_16x16x32_bf16(af[mi], bfr[ni], acc[mi][ni], 0, 0, 0);
    }

#pragma unroll
    for (int ni = 0; ni < 4; ni++) {
        int col = wn + ni * 16 + lr;
        float bia = bias[col];
#pragma unroll
        for (int mi = 0; mi < 4; mi++) {
#pragma unroll
            for (int j = 0; j < 4; j++) {
                int row = m0 + wm + mi * 16 + lk * 4 + j;
                if (row < M) C[(size_t)row * 128 + col] = (bf16)(acc[mi][ni][j] + bia);
            }
        }
    }
}

// ---- FUSED aggregation + per-relation GEMM + bias + BN-stats, v4.
// v3 post-mortem: VGPR pinned at 64 -> the "8-deep" gather pipeline couldn't
// hold 8 loads in flight (acc[8]=32 regs left no room); only 3126 waves total
// (30% occupancy) -> random-h gather latency nearly serial. v4 levers:
//   - 16-node tile, 2 waves/block, grid N/16=3125 -> 6250 waves (24/CU).
//   - each wave gathers 8 rows (~16 edges/relation: 2 batches of 8) and
//     computes a 16x64 output half -> acc[4] (16 VGPRs), launch_bounds(128,6)
//     (cap ~85 VGPR) so the 8-deep pipeline actually fits in registers.
//   - LDS tile stored as PACKED BF16 (last-wins store of the running sum;
//     edges of one dst are consecutive since csr is seg-sorted); tile = 4KB,
//     MFMA A-frags are direct bf16x8 reads (no f32->bf16 convert).
//   - 2 cheap 2-wave barriers per phase (store->read, read->overwrite);
//     MFMA + B-frag global loads sit after the 2nd barrier so they overlap
//     the next phase's gather.
// Swizzle: phys 16B-chunk = logical chunk ^ (row&7), same as k_gemm0.
__global__ __launch_bounds__(128, 6) void k_aggmm(const bf16* __restrict__ h, const int* __restrict__ row_off,
                                                  const int* __restrict__ csr, const bf16* __restrict__ BT,
                                                  const float* __restrict__ bias, float* __restrict__ C,
                                                  float* __restrict__ stats, int N, int R, int ldt) {
    __shared__ bf16 sTile[16 * 128];  // 4 KB
    __shared__ float csum[128], csum2[128];
    __shared__ int sOff[24];          // R*3 half-tile boundaries
    int tid = threadIdx.x;
    int lane = tid & 63, w = tid >> 6;
    int lr = lane & 15, lk = lane >> 4;
    int n0 = blockIdx.x * 16;
    int wn = w << 6;  // this wave's output col base
    if (tid < 128) { csum[tid] = 0.f; csum2[tid] = 0.f; }
    int nOff = R * 3;
    if (tid < nOff) {
        int r = tid / 3, ww = tid - r * 3;
        int node = n0 + (ww << 3);
        node = node < N ? node : N;
        sOff[tid] = row_off[(size_t)r * N + node];
    }
    int c0 = lane * 2;          // this lane's channel pair
    int c16l = lane >> 2;       // logical 16B chunk of that pair
    int within = (lane & 3) << 1;  // elem offset within chunk

    f32x4 zero4 = {0.f, 0.f, 0.f, 0.f};
    f32x4 acc[4];
#pragma unroll
    for (int ni = 0; ni < 4; ni++) acc[ni] = zero4;
    __syncthreads();  // sOff/csum visibility

    for (int r = 0; r < R; r++) {
        // ---- zero own 8 rows (WAR-safe: after previous phase's 2nd barrier)
        int4 z4 = {0, 0, 0, 0};
#pragma unroll
        for (int i = 0; i < 2; i++)
            *reinterpret_cast<int4*>(&sTile[(w << 10) + (i << 9) + (lane << 3)]) = z4;
        // ---- gather own 8 rows: register accumulate + last-wins packed store
        int beg = sOff[r * 3 + w];
        int end = sOff[r * 3 + w + 1];
        int cur = -1;
        float a0 = 0.f, a1 = 0.f;
        int e = beg;
        for (; e + 8 <= end; e += 8) {
            uint32_t pp[8], vv[8];
#pragma unroll
            for (int u = 0; u < 8; u++) pp[u] = (uint32_t)csr[e + u];
#pragma unroll
            for (int u = 0; u < 8; u++)
                vv[u] = *reinterpret_cast<const uint32_t*>(&h[(size_t)(pp[u] & 0xffffu) * 128 + c0]);
#pragma unroll
            for (int u = 0; u < 8; u++) {
                int dl = (int)(pp[u] >> 16) - n0;
                bool same = (dl == cur);
                a0 = (same ? a0 : 0.f) + bfbits2f(vv[u] & 0xffffu);
                a1 = (same ? a1 : 0.f) + bfbits2f(vv[u] >> 16);
                cur = dl;
                *reinterpret_cast<uint32_t*>(
                    &sTile[dl * 128 + (((c16l ^ (dl & 7)) << 3) | within)]) = pack2bf(a0, a1);
            }
        }
        for (; e < end; e++) {
            uint32_t p = (uint32_t)csr[e];
            uint32_t v = *reinterpret_cast<const uint32_t*>(&h[(size_t)(p & 0xffffu) * 128 + c0]);
            int dl = (int)(p >> 16) - n0;
            bool same = (dl == cur);
            a0 = (same ? a0 : 0.f) + bfbits2f(v & 0xffffu);
            a1 = (same ? a1 : 0.f) + bfbits2f(v >> 16);
            cur = dl;
            *reinterpret_cast<uint32_t*>(
                &sTile[dl * 128 + (((c16l ^ (dl & 7)) << 3) | within)]) = pack2bf(a0, a1);
        }
        __syncthreads();  // stores visible to both waves
        // ---- read A-fragments (shared 16-row tile)
        bf16x8 afr[4];
#pragma unroll
        for (int kk = 0; kk < 4; kk++) {
            int c = (kk << 2) + lk;
            afr[kk] = *reinterpret_cast<const bf16x8*>(&sTile[lr * 128 + ((c ^ (lr & 7)) << 3)]);
        }
        __syncthreads();  // reads done -> next phase may overwrite
        // ---- MFMA vs WcatT2 r-slice (B from L2; overlaps next phase's gather)
#pragma unroll
        for (int kk = 0; kk < 4; kk++) {
            int c = (kk << 2) + lk;
#pragma unroll
            for (int ni = 0; ni < 4; ni++) {
                int o = wn + (ni << 4) + lr;
                bf16x8 bfrag = *reinterpret_cast<const bf16x8*>(&BT[(size_t)o * ldt + (r << 7) + (c << 3)]);
                acc[ni] = __builtin_amdgcn_mfma_f32_16x16x32_bf16(afr[kk], bfrag, acc[ni], 0, 0, 0);
            }
        }
    }

    // ---- root phase: A-fragments straight from h
    {
        int grow = n0 + lr;
        grow = grow < N ? grow : N - 1;  // clamp; dup rows masked at C-write
#pragma unroll
        for (int kk = 0; kk < 4; kk++) {
            int c = (kk << 2) + lk;
            bf16x8 af = *reinterpret_cast<const bf16x8*>(&h[(size_t)grow * 128 + (c << 3)]);
#pragma unroll
            for (int ni = 0; ni < 4; ni++) {
                int o = wn + (ni << 4) + lr;
                bf16x8 bfrag = *reinterpret_cast<const bf16x8*>(&BT[(size_t)o * ldt + (R << 7) + (c << 3)]);
                acc[ni] = __builtin_amdgcn_mfma_f32_16x16x32_bf16(af, bfrag, acc[ni], 0, 0, 0);
            }
        }
    }

    // ---- epilogue: bias + conv write + fused BN stats
#pragma unroll
    for (int ni = 0; ni < 4; ni++) {
        int col = wn + (ni << 4) + lr;
        float bia = bias[col];
        float s = 0.f, s2 = 0.f;
#pragma unroll
        for (int j = 0; j < 4; j++) {
            int row = n0 + (lk << 2) + j;
            if (row < N) {
                float val = acc[ni][j] + bia;
                C[(size_t)row * 128 + col] = val;
                s += val;
                s2 += val * val;
            }
        }
        s += __shfl_xor(s, 16); s += __shfl_xor(s, 32);
        s2 += __shfl_xor(s2, 16); s2 += __shfl_xor(s2, 32);
        if (lk == 0) { atomicAdd(&csum[col], s); atomicAdd(&csum2[col], s2); }
    }
    __syncthreads();
    if (tid < 128) {
        atomicAdd(&stats[tid], csum[tid]);
        atomicAdd(&stats[128 + tid], csum2[tid]);
    }
}

// ---- finalize BN coefficients; also re-zeros stats for the next layer
__global__ void k_bnfin(float* __restrict__ stats, const float* __restrict__ gamma,
                        const float* __restrict__ beta, float* __restrict__ bnp, float invN) {
    int t = threadIdx.x;
    float mu = stats[t] * invN;
    float var = stats[128 + t] * invN - mu * mu;
    float sc = gamma[t] * rsqrtf(var + 1e-5f);
    bnp[t] = sc;
    bnp[128 + t] = beta[t] - mu * sc;
    stats[t] = 0.f;
    stats[128 + t] = 0.f;
}

// ---- BN + ReLU + cast to bf16 (layer 1) ----
__global__ void k_bnrelu(const float* __restrict__ conv, const float* __restrict__ bnp,
                         bf16* __restrict__ h, int N) {
    int total = N * 32;
    for (int i = blockIdx.x * blockDim.x + threadIdx.x; i < total; i += gridDim.x * blockDim.x) {
        int c4 = (i & 31) << 2;
        float4 v = *reinterpret_cast<const float4*>(&conv[(size_t)i * 4]);
        const float* vv = &v.x;
        uint64_t pk = 0;
#pragma unroll
        for (int j = 0; j < 4; j++) {
            int c = c4 + j;
            float val = fmaxf(vv[j] * bnp[c] + bnp[128 + c], 0.f);
            unsigned short us = __builtin_bit_cast(unsigned short, (bf16)val);
            pk |= (uint64_t)us << (16 * j);
        }
        *reinterpret_cast<uint64_t*>(&h[(size_t)i * 4]) = pk;
    }
}

// ---- layer 2: out[n] = sigmoid(relu(bn(conv[n])) . q + c), fused, f32 out ----
__global__ __launch_bounds__(256) void k_bnout(const float* __restrict__ conv, const float* __restrict__ bnp,
                                               const float* __restrict__ qc, float* __restrict__ out, int N) {
    int wi = threadIdx.x >> 6;
    int n = blockIdx.x * 4 + wi;
    if (n >= N) return;
    int lane = threadIdx.x & 63;
    int c0 = lane * 2;
    float2 v = *reinterpret_cast<const float2*>(&conv[(size_t)n * 128 + c0]);
    float v0 = fmaxf(v.x * bnp[c0] + bnp[128 + c0], 0.f);
    float v1 = fmaxf(v.y * bnp[c0 + 1] + bnp[128 + c0 + 1], 0.f);
    float s = v0 * qc[c0] + v1 * qc[c0 + 1];
#pragma unroll
    for (int d = 1; d < 64; d <<= 1) s += __shfl_xor(s, d);
    if (lane == 0) out[n] = 1.f / (1.f + expf(-(s + qc[128])));
}

extern "C" void kernel_launch(void* const* d_in, const int* in_sizes, int n_in,
                              void* d_out, int out_size, void* d_ws, size_t ws_size,
                              hipStream_t stream) {
    const float* x      = (const float*)d_in[0];
    const int*   ei     = (const int*)d_in[1];
    const int*   etype  = (const int*)d_in[2];
    const float* W1     = (const float*)d_in[3];
    const float* b1     = (const float*)d_in[4];
    const float* weight = (const float*)d_in[5];
    const float* root   = (const float*)d_in[6];
    const float* bias_c = (const float*)d_in[7];
    const float* gamma  = (const float*)d_in[8];
    const float* beta   = (const float*)d_in[9];
    const float* W2     = (const float*)d_in[10];
    const float* b2     = (const float*)d_in[11];
    const float* Wo     = (const float*)d_in[12];
    const float* bo     = (const float*)d_in[13];
    float* out = (float*)d_out;

    int H = in_sizes[4];            // 128
    int F = in_sizes[3] / H;        // 128
    int N = in_sizes[0] / F;        // 50000
    int E = in_sizes[2];            // 800000
    int R = in_sizes[5] / (H * H);  // 8
    int ldt = (R + 1) * H;          // 1152
    int M = R * N;                  // 400000 segments (seg = r*N + dst)

    const int* srcv = ei;
    const int* dstv = ei + E;

    char* p = (char*)d_ws;
    auto alloc = [&](size_t bytes) -> char* {
        char* r = p;
        p += (bytes + 255) & ~(size_t)255;
        return r;
    };
    bf16*  h       = (bf16*)alloc((size_t)N * H * 2);
    float* conv    = (float*)alloc((size_t)N * H * 4);
    bf16*  WcatT2  = (bf16*)alloc((size_t)ldt * H * 2);
    bf16*  W1T     = (bf16*)alloc((size_t)F * H * 2);
    float* qc      = (float*)alloc(129 * 4);
    int*   cnt     = (int*)alloc((size_t)M * 4);
    int*   row_off = (int*)alloc((size_t)(M + 1) * 4);
    int*   cursor  = (int*)alloc((size_t)M * 4);
    int*   csr     = (int*)alloc((size_t)E * 4);
    float* stats   = (float*)alloc(256 * 4);
    float* bnp     = (float*)alloc(256 * 4);
    int*   bsum    = (int*)alloc(2048 * 4);
    if ((size_t)(p - (char*)d_ws) > ws_size) return;

    int nb = (M + 255) / 256;   // 1563 (<= 2048 for N <= 65536, R <= 8)
    int pbase = (M + 7) / 8;    // seg-partition width for XCD-local csr fill

    hipMemsetAsync(cnt, 0, (size_t)M * 4, stream);
    hipMemsetAsync(stats, 0, 256 * 4, stream);
    k_prep<<<256, 256, 0, stream>>>(W1, weight, root, W1T, WcatT2, R, ldt);
    k_qprep<<<1, 128, 0, stream>>>(W2, b2, Wo, bo, qc);
    k_hist<<<1024, 256, 0, stream>>>(dstv, etype, cnt, E, N);
    k_scan_blk<<<nb, 256, 0, stream>>>(cnt, bsum, M);
    k_scan_top<<<1, 256, 0, stream>>>(bsum, nb);
    k_scan_apply<<<nb, 256, 0, stream>>>(cnt, bsum, row_off, cursor, M);
    k_fill<<<1024, 256, 0, stream>>>(srcv, dstv, etype, cursor, csr, E, N, pbase);

    int mb = (N + 127) / 128;
    k_gemm0<<<mb, 256, 0, stream>>>(x, W1T, b1, h, N);

    int ab = (N + 15) / 16;
    for (int l = 0; l < 2; l++) {
        k_aggmm<<<ab, 128, 0, stream>>>(h, row_off, csr, WcatT2, bias_c, conv, stats, N, R, ldt);
        k_bnfin<<<1, 128, 0, stream>>>(stats, gamma, beta, bnp, 1.f / (float)N);
        if (l == 0)
            k_bnrelu<<<2048, 256, 0, stream>>>(conv, bnp, h, N);
        else
            k_bnout<<<(N + 3) / 4, 256, 0, stream>>>(conv, bnp, qc, out, N);
    }
}

// Round 5
// 303.047 us; speedup vs baseline: 1.9859x; 1.9859x over previous
//
#include <hip/hip_runtime.h>
#include <stdint.h>

typedef __bf16 bf16;
typedef __bf16 bf16x8 __attribute__((ext_vector_type(8)));
typedef float f32x4 __attribute__((ext_vector_type(4)));

__device__ __forceinline__ float bfbits2f(uint32_t lo16) {
    uint32_t b = lo16 << 16;
    float f;
    __builtin_memcpy(&f, &b, 4);
    return f;
}

__device__ __forceinline__ uint32_t pack2bf(float a, float b) {
    uint32_t lo = __builtin_bit_cast(unsigned short, (bf16)a);
    uint32_t hi = __builtin_bit_cast(unsigned short, (bf16)b);
    return lo | (hi << 16);
}

__device__ __forceinline__ void gload_lds16(const void* g, void* l) {
    __builtin_amdgcn_global_load_lds((const __attribute__((address_space(1))) void*)g,
                                     (__attribute__((address_space(3))) void*)l, 16, 0, 0);
}

// ---- prep: W1T[h][f]=W1[f][h];  WcatT2[o][r*128+c]=weight[r][c][o],
// WcatT2[o][R*128+c]=root[c][o];  tail range computes qc (merged k_qprep):
// qc[i]=sum_j W2[i][j]*Wo[j], qc[128]=b2.Wo+bo
__global__ void k_prep(const float* __restrict__ W1, const float* __restrict__ weight,
                       const float* __restrict__ root, const float* __restrict__ W2,
                       const float* __restrict__ b2, const float* __restrict__ Wo,
                       const float* __restrict__ bo, bf16* __restrict__ W1T,
                       bf16* __restrict__ WcatT2, float* __restrict__ qc, int R, int ldt) {
    int total = 16384 * (R + 2);
    for (int i = blockIdx.x * blockDim.x + threadIdx.x; i < total + 129; i += gridDim.x * blockDim.x) {
        if (i < 16384) {
            int f = i >> 7, h = i & 127;
            W1T[h * 128 + f] = (bf16)W1[f * 128 + h];
        } else if (i < total) {
            int j = i - 16384;
            int r = j >> 14, rem = j & 16383, c = rem >> 7, o = rem & 127;
            float v = (r < R) ? weight[(size_t)(r * 128 + c) * 128 + o] : root[c * 128 + o];
            WcatT2[(size_t)o * ldt + r * 128 + c] = (bf16)v;
        } else {
            int t = i - total;
            if (t < 128) {
                float s = 0.f;
                for (int j = 0; j < 128; j++) s += W2[t * 128 + j] * Wo[j];
                qc[t] = s;
            } else {
                float c = bo[0];
                for (int j = 0; j < 128; j++) c += b2[j] * Wo[j];
                qc[128] = c;
            }
        }
    }
}

// ---- CSR build (dst-keyed, N segments; payload (etype<<16)|src) ----
__global__ void k_hist(const int* __restrict__ dst, int* __restrict__ cnt, int E) {
    for (int e = blockIdx.x * blockDim.x + threadIdx.x; e < E; e += gridDim.x * blockDim.x)
        atomicAdd(&cnt[dst[e]], 1);
}

__global__ __launch_bounds__(256) void k_scan_blk(const int* __restrict__ cnt, int* __restrict__ bsum, int N) {
    int i = blockIdx.x * 256 + threadIdx.x;
    int v = (i < N) ? cnt[i] : 0;
#pragma unroll
    for (int d = 1; d < 64; d <<= 1) v += __shfl_xor(v, d);
    __shared__ int ws[4];
    if ((threadIdx.x & 63) == 0) ws[threadIdx.x >> 6] = v;
    __syncthreads();
    if (threadIdx.x == 0) bsum[blockIdx.x] = ws[0] + ws[1] + ws[2] + ws[3];
}

__global__ __launch_bounds__(256) void k_scan_top(int* __restrict__ bsum, int nb) {
    __shared__ int s[256];
    int t = threadIdx.x;
    int v = (t < nb) ? bsum[t] : 0;
    s[t] = v;
    __syncthreads();
#pragma unroll
    for (int d = 1; d < 256; d <<= 1) {
        int u = (t >= d) ? s[t - d] : 0;
        __syncthreads();
        s[t] += u;
        __syncthreads();
    }
    if (t < nb) bsum[t] = s[t] - v;  // exclusive
}

__global__ __launch_bounds__(256) void k_scan_apply(const int* __restrict__ cnt, const int* __restrict__ bsum,
                                                    int* __restrict__ row_off, int* __restrict__ cursor, int N) {
    int b = blockIdx.x, t = threadIdx.x;
    int i = b * 256 + t;
    int v = (i < N) ? cnt[i] : 0;
    int lane = t & 63, wid = t >> 6;
    int incl = v;
#pragma unroll
    for (int d = 1; d < 64; d <<= 1) {
        int u = __shfl_up(incl, d);
        if (lane >= d) incl += u;
    }
    __shared__ int ws[4];
    if (lane == 63) ws[wid] = incl;
    __syncthreads();
    int woff = 0;
    for (int wj = 0; wj < 4; wj++)
        if (wj < wid) woff += ws[wj];
    int excl = bsum[b] + woff + incl - v;
    if (i < N) {
        row_off[i] = excl;
        cursor[i] = excl;
        if (i == N - 1) row_off[N] = excl + v;
    }
}

// XCD-partitioned CSR fill (round-12 profile: single-pass scatter wrote 54MB
// for a 3.2MB csr — every 4B store cost a full line writeback because stores
// to one line came from different (non-coherent) XCD L2s). Partition p =
// dst/pbase is handled only by blocks with blockIdx&7==p (round-robin block->
// XCD dispatch -> one XCD owns each contiguous csr region; lines fill fully
// before writeback). 8 consecutive blocks share one edge chunk.
__global__ void k_fill(const int* __restrict__ src, const int* __restrict__ dst,
                       const int* __restrict__ etype, int* __restrict__ cursor,
                       int* __restrict__ csr, int E, int pbase) {
    int p = blockIdx.x & 7;
    int bg = blockIdx.x >> 3;
    int nchunk = gridDim.x >> 3;
    int chunk = (E + nchunk - 1) / nchunk;
    int beg = bg * chunk, end = min(beg + chunk, E);
    int lo = p * pbase, hi = lo + pbase;
    for (int e = beg + (int)threadIdx.x; e < end; e += blockDim.x) {
        int d = dst[e];
        if (d >= lo && d < hi) {
            int pos = atomicAdd(&cursor[d], 1);
            csr[pos] = (etype[e] << 16) | src[e];  // requires N <= 65536
        }
    }
}

// ---- GEMM (layer 0): C[M x 128] = A_f32[M x 128] * B[128 x 128] (+bias), bf16 out
__global__ __launch_bounds__(256) void k_gemm0(const float* __restrict__ A, const bf16* __restrict__ BT,
                                               const float* __restrict__ bias, bf16* __restrict__ C, int M) {
    __shared__ bf16 sA[128 * 128];
    __shared__ bf16 sB[128 * 128];
    int tid = threadIdx.x;
    int m0 = blockIdx.x * 128;
#pragma unroll
    for (int i = 0; i < 8; i++) {
        int chunk = i * 256 + tid;
        int row = chunk >> 4, c16 = chunk & 15;
        int sw = ((c16 ^ (row & 7)) << 3);
        int gr = m0 + row;
        int4 va = {0, 0, 0, 0};
        if (gr < M) {
            const float* ap = A + (size_t)gr * 128 + (c16 << 3);
            float4 f0 = *reinterpret_cast<const float4*>(ap);
            float4 f1 = *reinterpret_cast<const float4*>(ap + 4);
            bf16 tmp[8] = {(bf16)f0.x, (bf16)f0.y, (bf16)f0.z, (bf16)f0.w,
                           (bf16)f1.x, (bf16)f1.y, (bf16)f1.z, (bf16)f1.w};
            __builtin_memcpy(&va, tmp, 16);
        }
        *reinterpret_cast<int4*>(&sA[row * 128 + sw]) = va;
        int4 vb = *reinterpret_cast<const int4*>(&BT[(size_t)row * 128 + (c16 << 3)]);
        *reinterpret_cast<int4*>(&sB[row * 128 + sw]) = vb;
    }
    __syncthreads();

    int lane = tid & 63, w = tid >> 6;
    int wm = (w >> 1) * 64, wn = (w & 1) * 64;
    int lr = lane & 15, lk = lane >> 4;
    f32x4 zero = {0.f, 0.f, 0.f, 0.f};
    f32x4 acc[4][4];
#pragma unroll
    for (int mi = 0; mi < 4; mi++)
#pragma unroll
        for (int ni = 0; ni < 4; ni++) acc[mi][ni] = zero;

#pragma unroll
    for (int kk = 0; kk < 4; kk++) {
        int c = (kk << 2) + lk;
        bf16x8 af[4], bfr[4];
#pragma unroll
        for (int mi = 0; mi < 4; mi++) {
            int r = wm + mi * 16 + lr;
            af[mi] = *reinterpret_cast<const bf16x8*>(&sA[r * 128 + ((c ^ (r & 7)) << 3)]);
        }
#pragma unroll
        for (int ni = 0; ni < 4; ni++) {
            int r = wn + ni * 16 + lr;
            bfr[ni] = *reinterpret_cast<const bf16x8*>(&sB[r * 128 + ((c ^ (r & 7)) << 3)]);
        }
#pragma unroll
        for (int mi = 0; mi < 4; mi++)
#pragma unroll
            for (int ni = 0; ni < 4; ni++)
                acc[mi][ni] = __builtin_amdgcn_mfma_f32_16x16x32_bf16(af[mi], bfr[ni], acc[mi][ni], 0, 0, 0);
    }

#pragma unroll
    for (int ni = 0; ni < 4; ni++) {
        int col = wn + ni * 16 + lr;
        float bia = bias[col];
#pragma unroll
        for (int mi = 0; mi < 4; mi++) {
#pragma unroll
            for (int j = 0; j < 4; j++) {
                int row = m0 + wm + mi * 16 + lk * 4 + j;
                if (row < M) C[(size_t)row * 128 + col] = (bf16)(acc[mi][ni][j] + bia);
            }
        }
    }
}

// ---- aggregation: G[n] = [agg_0[n], ..., agg_7[n]] (bf16, row length 1024)
// Branchless LDS accumulate + 4-deep software pipeline (r6/r7 lessons).
// r(N+5) change: G stores are NON-TEMPORAL. Round-0 counters: FETCH 85MB vs
// ~16MB cold input -> the 100MB G write stream was allocating through L3 and
// evicting h (12.8MB), forcing continual HBM re-fetch of h rows. nt stores
// bypass cache allocation; h stays L3-resident.
__global__ __launch_bounds__(128) void k_agg2(const bf16* __restrict__ h, const int* __restrict__ row_off,
                                              const int* __restrict__ csr, bf16* __restrict__ G, int N) {
    __shared__ float acc[2][8 * 128];
    int wi = threadIdx.x >> 6;
    int n = blockIdx.x * 2 + wi;
    if (n >= N) return;
    int lane = threadIdx.x & 63;
    int c0 = lane * 2;
    float* a = acc[wi];
#pragma unroll
    for (int i = 0; i < 16; i++) a[i * 64 + lane] = 0.f;
    int beg = row_off[n], end = row_off[n + 1];
    int i = beg;
    for (; i + 4 <= end; i += 4) {
        int p0 = csr[i], p1 = csr[i + 1], p2 = csr[i + 2], p3 = csr[i + 3];
        uint32_t v0 = *reinterpret_cast<const uint32_t*>(&h[(size_t)(p0 & 0xffff) * 128 + c0]);
        uint32_t v1 = *reinterpret_cast<const uint32_t*>(&h[(size_t)(p1 & 0xffff) * 128 + c0]);
        uint32_t v2 = *reinterpret_cast<const uint32_t*>(&h[(size_t)(p2 & 0xffff) * 128 + c0]);
        uint32_t v3 = *reinterpret_cast<const uint32_t*>(&h[(size_t)(p3 & 0xffff) * 128 + c0]);
        float* a0 = &a[(p0 >> 16) * 128 + c0];
        a0[0] += bfbits2f(v0 & 0xffffu); a0[1] += bfbits2f(v0 >> 16);
        float* a1 = &a[(p1 >> 16) * 128 + c0];
        a1[0] += bfbits2f(v1 & 0xffffu); a1[1] += bfbits2f(v1 >> 16);
        float* a2 = &a[(p2 >> 16) * 128 + c0];
        a2[0] += bfbits2f(v2 & 0xffffu); a2[1] += bfbits2f(v2 >> 16);
        float* a3 = &a[(p3 >> 16) * 128 + c0];
        a3[0] += bfbits2f(v3 & 0xffffu); a3[1] += bfbits2f(v3 >> 16);
    }
    for (; i < end; i++) {
        int p = csr[i];
        uint32_t v = *reinterpret_cast<const uint32_t*>(&h[(size_t)(p & 0xffff) * 128 + c0]);
        float* ap = &a[(p >> 16) * 128 + c0];
        ap[0] += bfbits2f(v & 0xffffu);
        ap[1] += bfbits2f(v >> 16);
    }
    size_t gbase = (size_t)n * 1024 + c0;
#pragma unroll
    for (int r = 0; r < 8; r++) {
        __builtin_nontemporal_store(pack2bf(a[r * 128 + c0], a[r * 128 + c0 + 1]),
                                    reinterpret_cast<uint32_t*>(&G[gbase + r * 128]));
    }
}

// ---- GEMM2: conv[M x 128] = [G | h][M x K] * Wcat[K x 128] + bias_c, f32 out
// r8 structure staged via global_load_lds width=16 (r12: 57->~40us).
// + fused BN-stats (column sum/sumsq -> stats[256]).
__global__ __launch_bounds__(256) void k_gemm2(const bf16* __restrict__ G, const bf16* __restrict__ hsrc,
                                               const bf16* __restrict__ BT, const float* __restrict__ bias,
                                               float* __restrict__ C, float* __restrict__ stats,
                                               int M, int K) {
    __shared__ bf16 sA[128 * 128];
    __shared__ bf16 sB[128 * 128];
    __shared__ float csum[128], csum2[128];
    int tid = threadIdx.x;
    if (tid < 128) { csum[tid] = 0.f; csum2[tid] = 0.f; }
    int m0 = blockIdx.x * 128;
    int lane = tid & 63, w = tid >> 6;
    int wm = (w >> 1) * 64, wn = (w & 1) * 64;
    int lr = lane & 15, lk = lane >> 4;
    int l4 = lane >> 4, c16 = lane & 15;
    f32x4 zero = {0.f, 0.f, 0.f, 0.f};
    f32x4 acc[4][4];
#pragma unroll
    for (int mi = 0; mi < 4; mi++)
#pragma unroll
        for (int ni = 0; ni < 4; ni++) acc[mi][ni] = zero;

    int KT = K >> 7;          // 9
    size_t ldg = (size_t)(K - 128);  // 1024 (G row stride)
    for (int kt = 0; kt < KT; kt++) {
        bool lastt = (kt == KT - 1);
        const bf16* Abase = lastt ? hsrc : G;
        size_t ldA = lastt ? 128 : ldg;
        int ka = lastt ? 0 : (kt << 7);
        int k0 = kt << 7;
#pragma unroll
        for (int i = 0; i < 8; i++) {
            int row = i * 16 + (w << 2) + l4;        // tile row for this lane's chunk
            int cs = (c16 ^ (row & 7)) << 3;         // pre-swizzled source col (elems)
            int gr = m0 + row;
            gr = gr < M ? gr : M - 1;                // clamp; dup rows masked at C-write
            gload_lds16(Abase + (size_t)gr * ldA + ka + cs, &sA[(i * 256 + (w << 6)) * 8]);
            gload_lds16(&BT[(size_t)row * K + k0 + cs], &sB[(i * 256 + (w << 6)) * 8]);
        }
        asm volatile("s_waitcnt vmcnt(0)" ::: "memory");
        __syncthreads();

#pragma unroll
        for (int kk = 0; kk < 4; kk++) {
            int c = (kk << 2) + lk;
            bf16x8 af[4], bfr[4];
#pragma unroll
            for (int mi = 0; mi < 4; mi++) {
                int r = wm + mi * 16 + lr;
                af[mi] = *reinterpret_cast<const bf16x8*>(&sA[r * 128 + ((c ^ (r & 7)) << 3)]);
            }
#pragma unroll
            for (int ni = 0; ni < 4; ni++) {
                int r = wn + ni * 16 + lr;
                bfr[ni] = *reinterpret_cast<const bf16x8*>(&sB[r * 128 + ((c ^ (r & 7)) << 3)]);
            }
#pragma unroll
            for (int mi = 0; mi < 4; mi++)
#pragma unroll
                for (int ni = 0; ni < 4; ni++)
                    acc[mi][ni] = __builtin_amdgcn_mfma_f32_16x16x32_bf16(af[mi], bfr[ni], acc[mi][ni], 0, 0, 0);
        }
        __syncthreads();
    }

    float ls[4], ls2[4];
#pragma unroll
    for (int ni = 0; ni < 4; ni++) { ls[ni] = 0.f; ls2[ni] = 0.f; }
#pragma unroll
    for (int ni = 0; ni < 4; ni++) {
        int col = wn + ni * 16 + lr;
        float bia = bias[col];
#pragma unroll
        for (int mi = 0; mi < 4; mi++) {
#pragma unroll
            for (int j = 0; j < 4; j++) {
                int row = m0 + wm + mi * 16 + lk * 4 + j;
                if (row < M) {
                    float val = acc[mi][ni][j] + bia;
                    C[(size_t)row * 128 + col] = val;
                    ls[ni] += val;
                    ls2[ni] += val * val;
                }
            }
        }
    }
#pragma unroll
    for (int ni = 0; ni < 4; ni++) {
        float s = ls[ni], s2 = ls2[ni];
        s += __shfl_xor(s, 16); s += __shfl_xor(s, 32);
        s2 += __shfl_xor(s2, 16); s2 += __shfl_xor(s2, 32);
        if (lk == 0) {
            int col = wn + ni * 16 + lr;
            atomicAdd(&csum[col], s);
            atomicAdd(&csum2[col], s2);
        }
    }
    __syncthreads();
    if (tid < 128) {
        atomicAdd(&stats[tid], csum[tid]);
        atomicAdd(&stats[128 + tid], csum2[tid]);
    }
}

// ---- finalize BN coefficients: bnp[c]=scale, bnp[128+c]=shift; re-zero stats
__global__ void k_bnfin(float* __restrict__ stats, const float* __restrict__ gamma,
                        const float* __restrict__ beta, float* __restrict__ bnp, float invN) {
    int t = threadIdx.x;
    float mu = stats[t] * invN;
    float var = stats[128 + t] * invN - mu * mu;
    float sc = gamma[t] * rsqrtf(var + 1e-5f);
    bnp[t] = sc;
    bnp[128 + t] = beta[t] - mu * sc;
    stats[t] = 0.f;
    stats[128 + t] = 0.f;
}

// ---- BN + ReLU + cast to bf16 (layer 1) ----
__global__ void k_bnrelu(const float* __restrict__ conv, const float* __restrict__ bnp,
                         bf16* __restrict__ h, int N) {
    int total = N * 32;
    for (int i = blockIdx.x * blockDim.x + threadIdx.x; i < total; i += gridDim.x * blockDim.x) {
        int c4 = (i & 31) << 2;
        float4 v = *reinterpret_cast<const float4*>(&conv[(size_t)i * 4]);
        const float* vv = &v.x;
        uint64_t pk = 0;
#pragma unroll
        for (int j = 0; j < 4; j++) {
            int c = c4 + j;
            float val = fmaxf(vv[j] * bnp[c] + bnp[128 + c], 0.f);
            unsigned short us = __builtin_bit_cast(unsigned short, (bf16)val);
            pk |= (uint64_t)us << (16 * j);
        }
        *reinterpret_cast<uint64_t*>(&h[(size_t)i * 4]) = pk;
    }
}

// ---- layer 2: out[n] = sigmoid(relu(bn(conv[n])) . q + c), fused, f32 out ----
__global__ __launch_bounds__(256) void k_bnout(const float* __restrict__ conv, const float* __restrict__ bnp,
                                               const float* __restrict__ qc, float* __restrict__ out, int N) {
    int wi = threadIdx.x >> 6;
    int n = blockIdx.x * 4 + wi;
    if (n >= N) return;
    int lane = threadIdx.x & 63;
    int c0 = lane * 2;
    float2 v = *reinterpret_cast<const float2*>(&conv[(size_t)n * 128 + c0]);
    float v0 = fmaxf(v.x * bnp[c0] + bnp[128 + c0], 0.f);
    float v1 = fmaxf(v.y * bnp[c0 + 1] + bnp[128 + c0 + 1], 0.f);
    float s = v0 * qc[c0] + v1 * qc[c0 + 1];
#pragma unroll
    for (int d = 1; d < 64; d <<= 1) s += __shfl_xor(s, d);
    if (lane == 0) out[n] = 1.f / (1.f + expf(-(s + qc[128])));
}

extern "C" void kernel_launch(void* const* d_in, const int* in_sizes, int n_in,
                              void* d_out, int out_size, void* d_ws, size_t ws_size,
                              hipStream_t stream) {
    const float* x      = (const float*)d_in[0];
    const int*   ei     = (const int*)d_in[1];
    const int*   etype  = (const int*)d_in[2];
    const float* W1     = (const float*)d_in[3];
    const float* b1     = (const float*)d_in[4];
    const float* weight = (const float*)d_in[5];
    const float* root   = (const float*)d_in[6];
    const float* bias_c = (const float*)d_in[7];
    const float* gamma  = (const float*)d_in[8];
    const float* beta   = (const float*)d_in[9];
    const float* W2     = (const float*)d_in[10];
    const float* b2     = (const float*)d_in[11];
    const float* Wo     = (const float*)d_in[12];
    const float* bo     = (const float*)d_in[13];
    float* out = (float*)d_out;

    int H = in_sizes[4];            // 128
    int F = in_sizes[3] / H;        // 128
    int N = in_sizes[0] / F;        // 50000
    int E = in_sizes[2];            // 800000
    int R = in_sizes[5] / (H * H);  // 8
    int ldt = (R + 1) * H;          // 1152

    const int* srcv = ei;
    const int* dstv = ei + E;

    char* p = (char*)d_ws;
    auto alloc = [&](size_t bytes) -> char* {
        char* r = p;
        p += (bytes + 255) & ~(size_t)255;
        return r;
    };
    bf16*  G       = (bf16*)alloc((size_t)N * (R * H) * 2);
    bf16*  h       = (bf16*)alloc((size_t)N * H * 2);
    float* conv    = (float*)alloc((size_t)N * H * 4);
    bf16*  WcatT2  = (bf16*)alloc((size_t)ldt * H * 2);
    bf16*  W1T     = (bf16*)alloc((size_t)F * H * 2);
    float* qc      = (float*)alloc(129 * 4);
    int*   cnt     = (int*)alloc((size_t)N * 4);
    int*   row_off = (int*)alloc((size_t)(N + 1) * 4);
    int*   cursor  = (int*)alloc((size_t)N * 4);
    int*   csr     = (int*)alloc((size_t)E * 4);
    float* stats   = (float*)alloc(256 * 4);
    float* bnp     = (float*)alloc(256 * 4);
    int*   bsum    = (int*)alloc(256 * 4);
    if ((size_t)(p - (char*)d_ws) > ws_size) return;

    int nb = (N + 255) / 256;  // <= 256 since N <= 65536 (required by csr packing)
    int pbase = (N + 7) / 8;   // dst-partition width for XCD-local csr fill

    hipMemsetAsync(cnt, 0, (size_t)N * 4, stream);
    hipMemsetAsync(stats, 0, 256 * 4, stream);
    k_prep<<<256, 256, 0, stream>>>(W1, weight, root, W2, b2, Wo, bo, W1T, WcatT2, qc, R, ldt);
    k_hist<<<1024, 256, 0, stream>>>(dstv, cnt, E);
    k_scan_blk<<<nb, 256, 0, stream>>>(cnt, bsum, N);
    k_scan_top<<<1, 256, 0, stream>>>(bsum, nb);
    k_scan_apply<<<nb, 256, 0, stream>>>(cnt, bsum, row_off, cursor, N);
    k_fill<<<1024, 256, 0, stream>>>(srcv, dstv, etype, cursor, csr, E, pbase);

    int mb = (N + 127) / 128;
    k_gemm0<<<mb, 256, 0, stream>>>(x, W1T, b1, h, N);

    for (int l = 0; l < 2; l++) {
        k_agg2<<<(N + 1) / 2, 128, 0, stream>>>(h, row_off, csr, G, N);
        k_gemm2<<<mb, 256, 0, stream>>>(G, h, WcatT2, bias_c, conv, stats, N, ldt);
        k_bnfin<<<1, 128, 0, stream>>>(stats, gamma, beta, bnp, 1.f / (float)N);
        if (l == 0)
            k_bnrelu<<<2048, 256, 0, stream>>>(conv, bnp, h, N);
        else
            k_bnout<<<(N + 3) / 4, 256, 0, stream>>>(conv, bnp, qc, out, N);
    }
}